// Round 6
// baseline (299.182 us; speedup 1.0000x reference)
//
#include <hip/hip_runtime.h>

// spike_seq: (T=1024, B=16384, 2) fp32, values EXACTLY 0.0f / 1.0f.
// w_exc=(1,2)={0.7,1.0}; w_inh=-1.0.
// Outputs flat-concat: spk_rec (T*B) ++ mem_rec (T*B), fp32.
//
// R6: scan rewritten as prepass (16 independent unpacks, pure ILP) +
// slim 8-inst recurrence, and LAUNCHED TWICE as an attribution probe
// (idempotent). Pack/emit byte-identical to R5.
#define T_LEN  1024
#define B_N    16384
#define CHUNKS 32
#define CLEN   (T_LEN / CHUNKS)   // 32 steps per emit chunk
#define TPW    16                 // timesteps per packed u32 (2 bits each)
#define NTC    (T_LEN / TPW)      // 64 words per neuron
#define GR     (NTC / 4)          // 16 uint4 groups per neuron

// Step semantics (proven absmax=0.015625 since R1, must not change):
//   cur_exc = fl(x0*w0) + fl(x1*w1)   [x0,x1 in {0,1} -> products exact,
//                                      so fmaf(x0,w0,x1*w1) is identical]
//   inh     = fl(0.6*inh) + x0        [separate mul+add: contract OFF]
//   cur     = cur_exc + fl(wi*inh)    [wi=-1.0 -> == cur_exc - inh exactly]
//   reset   = (mem - 1 > 0)           [== (mem > 1): Sterbenz-exact]
//   mem     = fl(0.9*mem) + cur, minus 1.0 if reset
__device__ __forceinline__ void neuron_step_core(float x0, float x1,
                                                 float w0, float w1, float wi,
                                                 float& mem, float& inh) {
#pragma clang fp contract(off)
  const float cur_exc = __builtin_fmaf(x0, w0, x1 * w1);
  inh = 0.6f * inh + x0;
  const float cur = cur_exc + wi * inh;
  const bool reset = (mem - 1.0f > 0.0f);
  const float m2 = 0.9f * mem + cur;
  mem = reset ? (m2 - 1.0f) : m2;
}

// ---- Phase 0: pack x into 2-bit codes (interleaved uint4 layout). ----
__global__ __launch_bounds__(256) void FMFM_pack(
    const float* __restrict__ x, unsigned* __restrict__ cbits) {
  const int tid = blockIdx.x * 256 + threadIdx.x;   // 524288 threads
  const int b2  = tid & (B_N / 2 - 1);              // neuron pair (8192)
  const int tc  = tid >> 13;                        // word index 0..NTC-1
  const float4* __restrict__ xp = (const float4*)x; // (T, B/2) float4

  unsigned bits0 = 0, bits1 = 0;
#pragma unroll
  for (int u = 0; u < TPW; ++u) {
    const int t = tc * TPW + u;
    const float4 v = xp[(size_t)t * (B_N / 2) + b2];
    bits0 |= ((v.x != 0.0f) ? 1u : 0u) << (2 * u);
    bits0 |= ((v.y != 0.0f) ? 2u : 0u) << (2 * u);
    bits1 |= ((v.z != 0.0f) ? 1u : 0u) << (2 * u);
    bits1 |= ((v.w != 0.0f) ? 2u : 0u) << (2 * u);
  }
  const size_t base = ((size_t)(tc >> 2) * B_N + 2 * b2) * 4 + (tc & 3);
  cbits[base]     = bits0;   // neuron 2*b2
  cbits[base + 4] = bits1;   // neuron 2*b2+1
}

// ---- Phase 1: serial carry scan. 256 blocks x 64 thr = 1 wave/CU.
// R6 rewrite: per 32-bit word, a PREPASS unpacks all 16 steps into
// cur_exc[]/x0f[] (independent ops -> fills issue slots), then a tight
// recurrence loop of 8 inst/step (chain ~16 cyc). This removes the
// dependent-latency exposure suspected to cost ~150 cyc/step at 1 wave/SIMD.
__global__ __launch_bounds__(64, 1) void FMFM_scan(
    const unsigned* __restrict__ cbits, const float* __restrict__ w_exc,
    const float* __restrict__ w_inh, float* __restrict__ carry) {
#pragma clang fp contract(off)
  const int b = blockIdx.x * 64 + threadIdx.x;
  const int lt = threadIdx.x;
  const float w0 = w_exc[0], w1 = w_exc[1];
  (void)w_inh;  // wi == -1.0 exactly: fl(wi*inh) == -inh bit-for-bit
  const uint4* __restrict__ cb4 = (const uint4*)cbits;

  __shared__ float lcar[2 * CHUNKS * 64];  // carries in LDS, flushed once

  float mem = 0.0f, inh = 0.0f;

  uint4 cur = cb4[b];            // group 0
  uint4 nxt = cb4[B_N + b];      // group 1

  for (int g = 0; g < GR; ++g) {                 // dynamic: body stays in I$
    const int gp = (g + 2 < GR) ? (g + 2) : (GR - 1);
    const uint4 pf = cb4[(size_t)gp * B_N + b];  // double-buffered lookahead
    const unsigned ws[4] = {cur.x, cur.y, cur.z, cur.w};
#pragma unroll
    for (int j = 0; j < 4; ++j) {
      if ((j & 1) == 0) {                        // word 4g+j even: chunk edge
        const int c = 2 * g + (j >> 1);          // state BEFORE t = c*CLEN
        lcar[(2 * c + 0) * 64 + lt] = mem;
        lcar[(2 * c + 1) * 64 + lt] = inh;
      }
      const unsigned w = ws[j];
      // Prepass: all 16 unpacks independent (bfe+cvt+mul+fma each).
      float ce[TPW], x0f[TPW];
#pragma unroll
      for (int u = 0; u < TPW; ++u) {
        const float a0 = (float)((w >> (2 * u)) & 1u);
        const float a1 = (float)((w >> (2 * u + 1)) & 1u);
        x0f[u] = a0;
        ce[u] = __builtin_fmaf(a0, w0, a1 * w1);  // exact products
      }
      // Recurrence: 8 inst/step.
#pragma unroll
      for (int u = 0; u < TPW; ++u) {
        inh = 0.6f * inh + x0f[u];       // mul + add (contract off)
        const float cur_v = ce[u] - inh; // == cur_exc + wi*inh, wi=-1 exact
        const bool r = (mem > 1.0f);     // == (mem-1>0), Sterbenz-exact
        const float m2 = 0.9f * mem + cur_v;
        mem = r ? (m2 - 1.0f) : m2;
      }
    }
    cur = nxt;
    nxt = pf;
  }

#pragma unroll
  for (int c = 0; c < CHUNKS; ++c) {
    carry[c * B_N + b]            = lcar[(2 * c + 0) * 64 + lt];
    carry[(CHUNKS + c) * B_N + b] = lcar[(2 * c + 1) * 64 + lt];
  }
}

// ---- Phase 2: per-chunk replay + output streaming (unchanged from R5). ----
__global__ __launch_bounds__(256) void FMFM_emit(
    const unsigned* __restrict__ cbits, const float* __restrict__ w_exc,
    const float* __restrict__ w_inh, const float* __restrict__ carry,
    float* __restrict__ out) {
#pragma clang fp contract(off)
  const int c = blockIdx.x >> 6;                       // 64 neuron-blocks/chunk
  const int b = ((blockIdx.x & 63) << 8) + threadIdx.x;
  const float w0 = w_exc[0], w1 = w_exc[1], wi = w_inh[0];

  float mem = carry[c * B_N + b];
  float inh = carry[(CHUNKS + c) * B_N + b];
  const uint2 wv = *(const uint2*)&cbits[((size_t)(c >> 1) * B_N + b) * 4 +
                                         (c & 1) * 2];
  const unsigned wa = wv.x, wb = wv.y;

  float* __restrict__ spk_out = out;
  float* __restrict__ mem_out = out + (size_t)T_LEN * B_N;
  const int tbase = c * CLEN;

#pragma unroll
  for (int u = 0; u < CLEN; ++u) {
    const unsigned w = (u < TPW) ? wa : wb;
    const int s = u & (TPW - 1);
    const float x0 = (float)((w >> (2 * s)) & 1u);
    const float x1 = (float)((w >> (2 * s + 1)) & 1u);
    neuron_step_core(x0, x1, w0, w1, wi, mem, inh);
    const float spk = (mem - 1.0f > 0.0f) ? 1.0f : 0.0f;
    const int t = tbase + u;
    spk_out[t * B_N + b] = spk;
    mem_out[t * B_N + b] = mem;
  }
}

extern "C" void kernel_launch(void* const* d_in, const int* in_sizes, int n_in,
                              void* d_out, int out_size, void* d_ws, size_t ws_size,
                              hipStream_t stream) {
  const float* x     = (const float*)d_in[0];
  const float* w_exc = (const float*)d_in[1];
  const float* w_inh = (const float*)d_in[2];
  float* out = (float*)d_out;

  unsigned* cbits = (unsigned*)d_ws;                                // 4 MB
  float*    carry = (float*)((char*)d_ws + (size_t)NTC * B_N * 4);  // 4 MB

  hipLaunchKernelGGL(FMFM_pack, dim3(NTC * (B_N / 2) / 256), dim3(256), 0,
                     stream, x, cbits);
  // ATTRIBUTION PROBE: scan launched twice (idempotent — second launch
  // recomputes identical carries). dur_us delta vs R5 isolates scan cost.
  hipLaunchKernelGGL(FMFM_scan, dim3(B_N / 64), dim3(64), 0, stream,
                     cbits, w_exc, w_inh, carry);
  hipLaunchKernelGGL(FMFM_scan, dim3(B_N / 64), dim3(64), 0, stream,
                     cbits, w_exc, w_inh, carry);
  hipLaunchKernelGGL(FMFM_emit, dim3(CHUNKS * (B_N / 256)), dim3(256), 0,
                     stream, cbits, w_exc, w_inh, carry, out);
}